// Round 15
// baseline (199.799 us; speedup 1.0000x reference)
//
#include <hip/hip_runtime.h>

// ConvCapsMatrix EM routing, MI355X. Inputs FP32, output FP32.
// R15 = R13 (512 thr, two-phase 44.5KB LDS reduction) +
//  (a) software-pipelined W prefetch: j-loop unrolled x2, next n's W loads
//      issued before current n's q/softmax chain (hides ~200cyc L2 latency
//      that sat inside every j's serial chain; VALUBusy pinned 41% at VGPR 64);
//  (b) mu/isig moved from 32 pinned VGPRs to packed float2 LDS table, paying
//      for the prefetch buffers. Thread=(o=t&31, ng=t>>5).

#define NN    288
#define EPSV  1e-8f

__device__ __forceinline__ void votes_from(const float4 w0, const float4 w1,
                                           const float4 w2, const float4 w3,
                                           const float* __restrict__ xr,
                                           float* __restrict__ V)
{
#pragma unroll
  for (int x = 0; x < 4; ++x) {
    const float4 xq = *(const float4*)(xr + (x << 2));
    V[x*4+0] = fmaf(xq.x, w0.x, fmaf(xq.y, w1.x, fmaf(xq.z, w2.x, xq.w*w3.x)));
    V[x*4+1] = fmaf(xq.x, w0.y, fmaf(xq.y, w1.y, fmaf(xq.z, w2.y, xq.w*w3.y)));
    V[x*4+2] = fmaf(xq.x, w0.z, fmaf(xq.y, w1.z, fmaf(xq.z, w2.z, xq.w*w3.z)));
    V[x*4+3] = fmaf(xq.x, w0.w, fmaf(xq.y, w1.w, fmaf(xq.z, w2.w, xq.w*w3.w)));
  }
}

__global__ __launch_bounds__(512, 4) void caps_em_kernel(
    const float* __restrict__ X, const float* __restrict__ A, const float* __restrict__ Wt,
    const float* __restrict__ Bu, const float* __restrict__ Ba,
    float* __restrict__ Out)
{
  __shared__ float  xp_s[NN*16];   // patch poses                 18432 B
  __shared__ float  a_s[NN];       // patch activations            1152 B
  __shared__ float  part[8*544];   // per-wave partials, 2-phase  17408 B
  __shared__ float  prs[8*32];     // per-wave sum Ra              1024 B
  __shared__ float  mu_t[512];     // mu[p][o]                     2048 B
  __shared__ float2 misg_t[512];   // {mu, 1/sig2}[p][o]           4096 B
  __shared__ float  lsig_t[512];   // log sig2[p][o]               2048 B
  __shared__ float  la_s[32];
  __shared__ float  slog_s[32];
  __shared__ float  aout_s[32];    // total ~46.6 KB -> 3 blocks/CU

  const int t    = threadIdx.x;
  const int o    = t & 31;
  const int ng   = t >> 5;        // 0..15
  const int wv   = t >> 6;        // 0..7
  const int lane = t & 63;

  const int pos = blockIdx.x;
  const int b  = pos / 144;
  const int r_ = pos - b*144;
  const int h  = r_ / 12;
  const int w  = r_ - (r_/12)*12;

  // ---- stage pose patch: x[b,h+k,w+l,c,p] -> xp_s[(kl*32+c)*16+p]
  for (int i = t; i < 1152; i += 512) {
    const int e   = i << 2;
    const int kl  = e >> 9;
    const int rem = e & 511;
    const int hy = h + kl/3, wx = w + (kl - (kl/3)*3);
    const float4 q = *(const float4*)(X + ((((b*14 + hy)*14 + wx) << 9) + rem));
    *(float4*)(xp_s + (kl << 9) + rem) = q;
  }
  for (int i = t; i < NN; i += 512) {
    const int kl = i >> 5, c = i & 31;
    const int hy = h + kl/3, wx = w + (kl - (kl/3)*3);
    a_s[i] = A[((b*14 + hy)*14 + wx)*32 + c];
  }
  __syncthreads();

  float la_r = 0.f, slog_r = 0.f;

  for (int it = 0; it < 3; ++it) {
    float S1[16], S2[16];
#pragma unroll
    for (int p = 0; p < 16; ++p) { S1[p] = 0.f; S2[p] = 0.f; }
    float rs = 0.f;

    // ---- preload W for j=0 (n = ng)
    float4 bA0, bA1, bA2, bA3, bB0, bB1, bB2, bB3;
    {
      const float* wp = Wt + (((ng << 5) + o) << 4);
      bA0 = *(const float4*)(wp);
      bA1 = *(const float4*)(wp + 4);
      bA2 = *(const float4*)(wp + 8);
      bA3 = *(const float4*)(wp + 12);
    }

#pragma unroll 1
    for (int jj = 0; jj < 9; ++jj) {
      const int nA = ng + (jj << 5);
      const int nB = nA + 16;
      // prefetch B while A's chain runs
      {
        const float* wp = Wt + (((nB << 5) + o) << 4);
        bB0 = *(const float4*)(wp);
        bB1 = *(const float4*)(wp + 4);
        bB2 = *(const float4*)(wp + 8);
        bB3 = *(const float4*)(wp + 12);
      }

#pragma unroll
      for (int half = 0; half < 2; ++half) {
        const int n = half ? nB : nA;
        float V[16];
        if (half) votes_from(bB0, bB1, bB2, bB3, xp_s + (n << 4), V);
        else      votes_from(bA0, bA1, bA2, bA3, xp_s + (n << 4), V);

        // prefetch next A right after A consumed (in flight during B's chain)
        if (!half && jj < 8) {
          const float* wp = Wt + ((((nA + 32) << 5) + o) << 4);
          bA0 = *(const float4*)(wp);
          bA1 = *(const float4*)(wp + 4);
          bA2 = *(const float4*)(wp + 8);
          bA3 = *(const float4*)(wp + 12);
        }

        float ra;
        if (it == 0) {
          ra = a_s[n] * (1.0f/32.0f);
        } else {
          // logp = -0.5*( sum_p (V-mu)^2*isig + slog ), mu/isig from LDS
          float q = slog_r;
#pragma unroll
          for (int p = 0; p < 16; ++p) {
            const float2 ms = misg_t[p*32 + o];
            const float d = V[p] - ms.x;
            q = fmaf(d*d, ms.y, q);
          }
          float z = la_r - 0.5f*q;
          float m = z;
#pragma unroll
          for (int msk = 16; msk >= 1; msk >>= 1) m = fmaxf(m, __shfl_xor(m, msk));
          const float ev = __expf(z - m);
          float s = ev;
#pragma unroll
          for (int msk = 16; msk >= 1; msk >>= 1) s += __shfl_xor(s, msk);
          ra = (ev / s) * a_s[n];
        }
        rs += ra;
#pragma unroll
        for (int p = 0; p < 16; ++p) {
          const float rv = ra * V[p];
          S1[p] += rv;
          S2[p] = fmaf(rv, V[p], S2[p]);
        }
      }
    }

    // ---- pair-combine ng via lane^32
#pragma unroll
    for (int p = 0; p < 16; ++p) {
      S1[p] += __shfl_xor(S1[p], 32);
      S2[p] += __shfl_xor(S2[p], 32);
    }
    rs += __shfl_xor(rs, 32);

    // ---- phase A: S1 partials -> mu
    if (lane < 32) {
      float* p1 = part + wv*544 + o*17;
#pragma unroll
      for (int p = 0; p < 16; ++p) p1[p] = S1[p];
      prs[wv*32 + o] = rs;
    }
    __syncthreads();
    {
      const int pi = t >> 5, oo = t & 31;
      float s1 = 0.f, rsum = EPSV;
#pragma unroll
      for (int g = 0; g < 8; ++g) {
        s1   += part[g*544 + oo*17 + pi];
        rsum += prs[(g << 5) + oo];
      }
      mu_t[pi*32 + oo] = s1 / rsum;
    }
    __syncthreads();

    // ---- phase B: S2 partials -> sig2 (var = s2/rs - mu^2, clamped)
    if (lane < 32) {
      float* p2 = part + wv*544 + o*17;
#pragma unroll
      for (int p = 0; p < 16; ++p) p2[p] = S2[p];
    }
    __syncthreads();
    {
      const int pi = t >> 5, oo = t & 31;
      float s2 = 0.f, rsum = EPSV;
#pragma unroll
      for (int g = 0; g < 8; ++g) {
        s2   += part[g*544 + oo*17 + pi];
        rsum += prs[(g << 5) + oo];
      }
      const float mu = mu_t[pi*32 + oo];
      float var = s2 / rsum - mu*mu;
      var = fmaxf(var, 0.f);
      const float sg = var + EPSV;
      misg_t[pi*32 + oo] = make_float2(mu, 1.0f / sg);
      lsig_t[pi*32 + oo] = __logf(sg);
    }
    __syncthreads();

    // ---- E2: cost, a_out per o
    if (t < 32) {
      float rsum = EPSV;
#pragma unroll
      for (int g = 0; g < 8; ++g) rsum += prs[(g << 5) + t];
      float slog = 0.f;
#pragma unroll
      for (int p = 0; p < 16; ++p) slog += lsig_t[p*32 + t];
      const float bu = Bu[t];
      const float ba = Ba[t];
      const float cost = rsum * (16.0f*bu + 0.5f*slog);
      const float av = 1.0f / (1.0f + __expf(-(ba - cost)));   // LAM=1
      aout_s[t] = av;
      la_s[t]   = __logf(av + EPSV);
      slog_s[t] = slog;
    }
    __syncthreads();

    if (it < 2) {
      slog_r = slog_s[o];
      la_r   = la_s[o];
    }
  }

  // ---- outputs (fp32): pose = mu (B,Ho,Wo,OC,M,M) then a_out (B,Ho,Wo,OC)
  {
    const int oo = t >> 4, pi = t & 15;
    Out[pos*512 + t] = mu_t[pi*32 + oo];
  }
  if (t < 32) Out[294912 + pos*32 + t] = aout_s[t];
}

extern "C" void kernel_launch(void* const* d_in, const int* in_sizes, int n_in,
                              void* d_out, int out_size, void* d_ws, size_t ws_size,
                              hipStream_t stream) {
  (void)in_sizes; (void)n_in; (void)d_ws; (void)ws_size; (void)out_size;
  const float* X  = (const float*)d_in[0];
  const float* A  = (const float*)d_in[1];
  const float* Wt = (const float*)d_in[2];
  const float* Bu = (const float*)d_in[3];
  const float* Ba = (const float*)d_in[4];
  float* Out = (float*)d_out;
  hipLaunchKernelGGL(caps_em_kernel, dim3(576), dim3(512), 0, stream,
                     X, A, Wt, Bu, Ba, Out);
}

// Round 17
// 168.491 us; speedup vs baseline: 1.1858x; 1.1858x over previous
//
#include <hip/hip_runtime.h>

// ConvCapsMatrix EM routing, MI355X. Inputs FP32, output FP32.
// R17 = R16 with the DPP ctrl as a template parameter (builtin requires an
// integer-constant expression; R16 passed a runtime int -> compile error).
// Softmax butterflies on the VALU pipe: xor1=quad_perm 0xB1, xor2=0x4E,
// xor4(within 8)=row_half_mirror 0x141 (valid: quads uniform after level 2),
// xor8(within 16)=row_mirror 0x140, xor16=one ds_swizzle 0x401F.
// q-chain split into 4 parallel accumulators.
// Base: R13 (512 thr, two-phase 44.5KB LDS reduction, 3 blocks/CU).

#define NN    288
#define EPSV  1e-8f

template <int CTRL>
__device__ __forceinline__ float dppf(float v) {
  return __int_as_float(__builtin_amdgcn_update_dpp(
      0, __float_as_int(v), CTRL, 0xf, 0xf, true));
}
__device__ __forceinline__ float swz16(float v) {   // lane ^ 16 within 32-groups
  return __int_as_float(__builtin_amdgcn_ds_swizzle(__float_as_int(v), 0x401F));
}
// reduce over each 32-lane half (all lanes receive the result)
__device__ __forceinline__ float red_max32(float v) {
  v = fmaxf(v, dppf<0xB1>(v));    // xor1  (quad_perm 1,0,3,2)
  v = fmaxf(v, dppf<0x4E>(v));    // xor2  (quad_perm 2,3,0,1)
  v = fmaxf(v, dppf<0x141>(v));   // row_half_mirror: other quad of 8
  v = fmaxf(v, dppf<0x140>(v));   // row_mirror: other 8 of 16
  v = fmaxf(v, swz16(v));         // other 16 of 32
  return v;
}
__device__ __forceinline__ float red_sum32(float v) {
  v += dppf<0xB1>(v);
  v += dppf<0x4E>(v);
  v += dppf<0x141>(v);
  v += dppf<0x140>(v);
  v += swz16(v);
  return v;
}

__device__ __forceinline__ void compute_votes(const float* __restrict__ Wt,
                                              const float* __restrict__ xp_s,
                                              int n, int o, float* __restrict__ V)
{
  // W[k,l,c,o,y,z] flat = (n*32+o)*16 + y*4+z
  float Wf[16];
  {
    const float* wp = Wt + (((n << 5) + o) << 4);
#pragma unroll
    for (int i = 0; i < 4; ++i) {
      const float4 q = *(const float4*)(wp + (i << 2));
      Wf[i*4+0]=q.x; Wf[i*4+1]=q.y; Wf[i*4+2]=q.z; Wf[i*4+3]=q.w;
    }
  }
  float xv[16];
  {
    const float* xr = xp_s + (n << 4);
#pragma unroll
    for (int i = 0; i < 4; ++i) {
      const float4 q = *(const float4*)(xr + (i << 2));
      xv[i*4+0]=q.x; xv[i*4+1]=q.y; xv[i*4+2]=q.z; xv[i*4+3]=q.w;
    }
  }
#pragma unroll
  for (int xi = 0; xi < 4; ++xi)
#pragma unroll
    for (int z = 0; z < 4; ++z)
      V[xi*4+z] = fmaf(xv[xi*4+0], Wf[z],
                  fmaf(xv[xi*4+1], Wf[4+z],
                  fmaf(xv[xi*4+2], Wf[8+z],
                       xv[xi*4+3]* Wf[12+z])));
}

__global__ __launch_bounds__(512, 4) void caps_em_kernel(
    const float* __restrict__ X, const float* __restrict__ A, const float* __restrict__ Wt,
    const float* __restrict__ Bu, const float* __restrict__ Ba,
    float* __restrict__ Out)
{
  __shared__ float xp_s[NN*16];   // patch poses                 18432 B
  __shared__ float a_s[NN];       // patch activations            1152 B
  __shared__ float part[8*544];   // per-wave partials, 2-phase  17408 B
  __shared__ float prs[8*32];     // per-wave sum Ra              1024 B
  __shared__ float mu_t[512];     // mu[p][o]                     2048 B
  __shared__ float isig_t[512];   // 1/sig2[p][o]                 2048 B
  __shared__ float lsig_t[512];   // log sig2[p][o]               2048 B
  __shared__ float la_s[32];
  __shared__ float slog_s[32];
  __shared__ float aout_s[32];    // total ~44.5 KB -> 3 blocks/CU

  const int t    = threadIdx.x;
  const int o    = t & 31;
  const int ng   = t >> 5;        // 0..15
  const int wv   = t >> 6;        // 0..7
  const int lane = t & 63;

  const int pos = blockIdx.x;
  const int b  = pos / 144;
  const int r_ = pos - b*144;
  const int h  = r_ / 12;
  const int w  = r_ - (r_/12)*12;

  // ---- stage pose patch: x[b,h+k,w+l,c,p] -> xp_s[(kl*32+c)*16+p]
  for (int i = t; i < 1152; i += 512) {
    const int e   = i << 2;
    const int kl  = e >> 9;
    const int rem = e & 511;
    const int hy = h + kl/3, wx = w + (kl - (kl/3)*3);
    const float4 q = *(const float4*)(X + ((((b*14 + hy)*14 + wx) << 9) + rem));
    *(float4*)(xp_s + (kl << 9) + rem) = q;
  }
  for (int i = t; i < NN; i += 512) {
    const int kl = i >> 5, c = i & 31;
    const int hy = h + kl/3, wx = w + (kl - (kl/3)*3);
    a_s[i] = A[((b*14 + hy)*14 + wx)*32 + c];
  }
  __syncthreads();

  // per-thread cached routing state (o fixed per thread)
  float mu_r[16], isig_r[16];
  float la_r = 0.f, slog_r = 0.f;
#pragma unroll
  for (int p = 0; p < 16; ++p) { mu_r[p] = 0.f; isig_r[p] = 0.f; }

  for (int it = 0; it < 3; ++it) {
    // ========== fused stats pass: Ra, sum Ra*V, sum Ra*V^2 ==========
    float S1[16], S2[16];
#pragma unroll
    for (int p = 0; p < 16; ++p) { S1[p] = 0.f; S2[p] = 0.f; }
    float rs = 0.f;

#pragma unroll 1
    for (int j = 0; j < 18; ++j) {
      const int n = ng + (j << 4);
      float V[16];
      compute_votes(Wt, xp_s, n, o, V);

      float ra;
      if (it == 0) {
        ra = a_s[n] * (1.0f/32.0f);
      } else {
        // logp = -0.5*( sum_p (V-mu)^2*isig + slog ), 4 parallel chains
        float q0 = 0.f, q1 = 0.f, q2 = 0.f, q3 = 0.f;
#pragma unroll
        for (int p = 0; p < 4; ++p) {
          float d;
          d = V[p]      - mu_r[p];      q0 = fmaf(d*d, isig_r[p],      q0);
          d = V[p+4]    - mu_r[p+4];    q1 = fmaf(d*d, isig_r[p+4],    q1);
          d = V[p+8]    - mu_r[p+8];    q2 = fmaf(d*d, isig_r[p+8],    q2);
          d = V[p+12]   - mu_r[p+12];   q3 = fmaf(d*d, isig_r[p+12],   q3);
        }
        const float q = slog_r + ((q0 + q1) + (q2 + q3));
        const float z = la_r - 0.5f*q;
        // softmax over the 32 o's (DPP butterflies, one swizzle for xor16)
        const float m  = red_max32(z);
        const float ev = __expf(z - m);
        const float s  = red_sum32(ev);
        ra = (ev / s) * a_s[n];
      }
      rs += ra;
#pragma unroll
      for (int p = 0; p < 16; ++p) {
        const float rv = ra * V[p];
        S1[p] += rv;
        S2[p] = fmaf(rv, V[p], S2[p]);
      }
    }

    // ---- pair-combine ng via lane^32
#pragma unroll
    for (int p = 0; p < 16; ++p) {
      S1[p] += __shfl_xor(S1[p], 32);
      S2[p] += __shfl_xor(S2[p], 32);
    }
    rs += __shfl_xor(rs, 32);

    // ---- phase A: S1 partials -> mu
    if (lane < 32) {
      float* p1 = part + wv*544 + o*17;
#pragma unroll
      for (int p = 0; p < 16; ++p) p1[p] = S1[p];
      prs[wv*32 + o] = rs;
    }
    __syncthreads();
    {
      const int pi = t >> 5, oo = t & 31;   // 512 threads cover all (p,o)
      float s1 = 0.f, rsum = EPSV;
#pragma unroll
      for (int g = 0; g < 8; ++g) {
        s1   += part[g*544 + oo*17 + pi];
        rsum += prs[(g << 5) + oo];
      }
      mu_t[pi*32 + oo] = s1 / rsum;
    }
    __syncthreads();

    // ---- phase B: S2 partials -> sig2 (var = s2/rs - mu^2, clamped)
    if (lane < 32) {
      float* p2 = part + wv*544 + o*17;
#pragma unroll
      for (int p = 0; p < 16; ++p) p2[p] = S2[p];
    }
    __syncthreads();
    {
      const int pi = t >> 5, oo = t & 31;
      float s2 = 0.f, rsum = EPSV;
#pragma unroll
      for (int g = 0; g < 8; ++g) {
        s2   += part[g*544 + oo*17 + pi];
        rsum += prs[(g << 5) + oo];
      }
      const float mu = mu_t[pi*32 + oo];
      float var = s2 / rsum - mu*mu;
      var = fmaxf(var, 0.f);
      const float sg = var + EPSV;
      isig_t[pi*32 + oo] = 1.0f / sg;
      lsig_t[pi*32 + oo] = __logf(sg);
    }
    __syncthreads();

    // ---- E2: cost, a_out per o
    if (t < 32) {
      float rsum = EPSV;
#pragma unroll
      for (int g = 0; g < 8; ++g) rsum += prs[(g << 5) + t];
      float slog = 0.f;
#pragma unroll
      for (int p = 0; p < 16; ++p) slog += lsig_t[p*32 + t];
      const float bu = Bu[t];
      const float ba = Ba[t];
      const float cost = rsum * (16.0f*bu + 0.5f*slog);
      const float av = 1.0f / (1.0f + __expf(-(ba - cost)));   // LAM=1
      aout_s[t] = av;
      la_s[t]   = __logf(av + EPSV);
      slog_s[t] = slog;
    }
    __syncthreads();

    if (it < 2) {
#pragma unroll
      for (int p = 0; p < 16; ++p) {
        mu_r[p]   = mu_t[p*32 + o];
        isig_r[p] = isig_t[p*32 + o];
      }
      slog_r = slog_s[o];
      la_r   = la_s[o];
    }
  }

  // ---- outputs (fp32): pose = mu (B,Ho,Wo,OC,M,M) then a_out (B,Ho,Wo,OC)
  {
    const int oo = t >> 4, pi = t & 15;     // t < 512
    Out[pos*512 + t] = mu_t[pi*32 + oo];
  }
  if (t < 32) Out[294912 + pos*32 + t] = aout_s[t];
}

extern "C" void kernel_launch(void* const* d_in, const int* in_sizes, int n_in,
                              void* d_out, int out_size, void* d_ws, size_t ws_size,
                              hipStream_t stream) {
  (void)in_sizes; (void)n_in; (void)d_ws; (void)ws_size; (void)out_size;
  const float* X  = (const float*)d_in[0];
  const float* A  = (const float*)d_in[1];
  const float* Wt = (const float*)d_in[2];
  const float* Bu = (const float*)d_in[3];
  const float* Ba = (const float*)d_in[4];
  float* Out = (float*)d_out;
  hipLaunchKernelGGL(caps_em_kernel, dim3(576), dim3(512), 0, stream,
                     X, A, Wt, Bu, Ba, Out);
}

// Round 18
// 162.412 us; speedup vs baseline: 1.2302x; 1.0374x over previous
//
#include <hip/hip_runtime.h>

// ConvCapsMatrix EM routing, MI355X. Inputs FP32, output FP32.
// R18: multi-launch split. Each EM iteration's stats pass runs as 1152 blocks
// (pos x n-half, 144 n's each) -> 9216 waves (2x wave supply; R10-R17 showed
// VALUBusy pinned ~43% at 4608 waves regardless of chain tweaks). State
// (mu/isig/aout) is recomputed per-block from the previous launch's partials
// (launch order = sync). Partials double-buffered in d_ws by parity.
// Launches: S0 -> S1 -> S2 -> F. j-body identical to R17 (DPP softmax).

#define EPSV 1e-8f

template <int CTRL>
__device__ __forceinline__ float dppf(float v) {
  return __int_as_float(__builtin_amdgcn_update_dpp(
      0, __float_as_int(v), CTRL, 0xf, 0xf, true));
}
__device__ __forceinline__ float swz16(float v) {   // lane ^ 16 within 32-groups
  return __int_as_float(__builtin_amdgcn_ds_swizzle(__float_as_int(v), 0x401F));
}
__device__ __forceinline__ float red_max32(float v) {
  v = fmaxf(v, dppf<0xB1>(v));
  v = fmaxf(v, dppf<0x4E>(v));
  v = fmaxf(v, dppf<0x141>(v));
  v = fmaxf(v, dppf<0x140>(v));
  v = fmaxf(v, swz16(v));
  return v;
}
__device__ __forceinline__ float red_sum32(float v) {
  v += dppf<0xB1>(v);
  v += dppf<0x4E>(v);
  v += dppf<0x141>(v);
  v += dppf<0x140>(v);
  v += swz16(v);
  return v;
}

__device__ __forceinline__ void compute_votes(const float* __restrict__ Wt,
                                              const float* __restrict__ xr,
                                              int n, int o, float* __restrict__ V)
{
  // W[k,l,c,o,y,z] flat = (n*32+o)*16 + y*4+z ; xr = local pose row (16 f)
  float Wf[16];
  {
    const float* wp = Wt + (((n << 5) + o) << 4);
#pragma unroll
    for (int i = 0; i < 4; ++i) {
      const float4 q = *(const float4*)(wp + (i << 2));
      Wf[i*4+0]=q.x; Wf[i*4+1]=q.y; Wf[i*4+2]=q.z; Wf[i*4+3]=q.w;
    }
  }
  float xv[16];
#pragma unroll
  for (int i = 0; i < 4; ++i) {
    const float4 q = *(const float4*)(xr + (i << 2));
    xv[i*4+0]=q.x; xv[i*4+1]=q.y; xv[i*4+2]=q.z; xv[i*4+3]=q.w;
  }
#pragma unroll
  for (int xi = 0; xi < 4; ++xi)
#pragma unroll
    for (int z = 0; z < 4; ++z)
      V[xi*4+z] = fmaf(xv[xi*4+0], Wf[z],
                  fmaf(xv[xi*4+1], Wf[4+z],
                  fmaf(xv[xi*4+2], Wf[8+z],
                       xv[xi*4+3]* Wf[12+z])));
}

// ---- stats kernel: one block per (pos, half). Writes partials to cur.
// partial layout per block: [0..511] S1(p*32+o), [512..1023] S2, [1024..1055] rs(o)
__global__ __launch_bounds__(512, 4) void caps_stats(
    const float* __restrict__ X, const float* __restrict__ A, const float* __restrict__ Wt,
    const float* __restrict__ Bu, const float* __restrict__ Ba,
    const float* __restrict__ prev, float* __restrict__ cur, int it)
{
  __shared__ float xp_s[144*16];   // half-patch poses            9216 B
  __shared__ float a_s[144];       // half-patch activations       576 B
  __shared__ float part[8*544];    // per-wave partials, 2-phase 17408 B
  __shared__ float prs[8*32];      // per-wave sum Ra             1024 B
  __shared__ float mu_t[512], isig_t[512], lsig_t[512];        // 6144 B
  __shared__ float la_s[32], slog_s[32], rs_s[32];

  const int t    = threadIdx.x;
  const int o    = t & 31;
  const int ng   = t >> 5;        // 0..15
  const int wv   = t >> 6;        // 0..7
  const int lane = t & 63;

  const int bid  = blockIdx.x;
  const int pos  = bid >> 1;
  const int half = bid & 1;
  const int b  = pos / 144;
  const int r_ = pos - b*144;
  const int h  = r_ / 12;
  const int w  = r_ - (r_/12)*12;
  const int nbase = half * 144;

  // ---- stage this half's 144 pose rows + activations
  for (int i = t; i < 576; i += 512) {       // 576 float4 chunks
    const int r  = i >> 2, q4 = i & 3;
    const int n  = nbase + r;
    const int kl = n >> 5, c = n & 31;
    const int hy = h + kl/3, wx = w + (kl - (kl/3)*3);
    const float4 v = *(const float4*)(X + ((((b*14+hy)*14+wx) << 9) + (c << 4) + (q4 << 2)));
    *(float4*)(xp_s + (r << 4) + (q4 << 2)) = v;
  }
  if (t < 144) {
    const int n  = nbase + t;
    const int kl = n >> 5, c = n & 31;
    const int hy = h + kl/3, wx = w + (kl - (kl/3)*3);
    a_s[t] = A[((b*14+hy)*14+wx)*32 + c];
  }

  float mu_r[16], isig_r[16];
  float la_r = 0.f, slog_r = 0.f;

  if (it > 0) {
    // ---- recompute routing state from prev partials (both halves)
    {
      const int pi = t >> 5, oo = t & 31;
      const float* h0 = prev + (pos*2+0)*1056;
      const float* h1 = prev + (pos*2+1)*1056;
      const int idx = pi*32 + oo;
      const float s1   = h0[idx]       + h1[idx];
      const float s2   = h0[512+idx]   + h1[512+idx];
      const float rsum = h0[1024+oo]   + h1[1024+oo] + EPSV;
      const float mu = s1 / rsum;
      float var = s2 / rsum - mu*mu;
      var = fmaxf(var, 0.f);
      const float sg = var + EPSV;
      mu_t[idx]   = mu;
      isig_t[idx] = 1.0f / sg;
      lsig_t[idx] = __logf(sg);
      if (pi == 0) rs_s[oo] = rsum;
    }
    __syncthreads();                        // also covers staging
    if (t < 32) {
      float slog = 0.f;
#pragma unroll
      for (int p = 0; p < 16; ++p) slog += lsig_t[p*32 + t];
      const float cost = rs_s[t] * (16.0f*Bu[t] + 0.5f*slog);
      const float av = 1.0f / (1.0f + __expf(-(Ba[t] - cost)));   // LAM=1
      la_s[t]   = __logf(av + EPSV);
      slog_s[t] = slog;
    }
    __syncthreads();
#pragma unroll
    for (int p = 0; p < 16; ++p) { mu_r[p] = mu_t[p*32 + o]; isig_r[p] = isig_t[p*32 + o]; }
    slog_r = slog_s[o];
    la_r   = la_s[o];
  } else {
#pragma unroll
    for (int p = 0; p < 16; ++p) { mu_r[p] = 0.f; isig_r[p] = 0.f; }
    __syncthreads();                        // staging visibility
  }

  // ---- fused stats pass over this half's n's
  float S1[16], S2[16];
#pragma unroll
  for (int p = 0; p < 16; ++p) { S1[p] = 0.f; S2[p] = 0.f; }
  float rs = 0.f;

#pragma unroll 1
  for (int j = 0; j < 9; ++j) {
    const int nl = ng + (j << 4);           // local row 0..143
    const int n  = nbase + nl;              // global n for W
    float V[16];
    compute_votes(Wt, xp_s + (nl << 4), n, o, V);

    float ra;
    if (it == 0) {
      ra = a_s[nl] * (1.0f/32.0f);
    } else {
      float q0 = 0.f, q1 = 0.f, q2 = 0.f, q3 = 0.f;
#pragma unroll
      for (int p = 0; p < 4; ++p) {
        float d;
        d = V[p]    - mu_r[p];    q0 = fmaf(d*d, isig_r[p],    q0);
        d = V[p+4]  - mu_r[p+4];  q1 = fmaf(d*d, isig_r[p+4],  q1);
        d = V[p+8]  - mu_r[p+8];  q2 = fmaf(d*d, isig_r[p+8],  q2);
        d = V[p+12] - mu_r[p+12]; q3 = fmaf(d*d, isig_r[p+12], q3);
      }
      const float q = slog_r + ((q0 + q1) + (q2 + q3));
      const float z = la_r - 0.5f*q;
      const float m  = red_max32(z);
      const float ev = __expf(z - m);
      const float s  = red_sum32(ev);
      ra = (ev / s) * a_s[nl];
    }
    rs += ra;
#pragma unroll
    for (int p = 0; p < 16; ++p) {
      const float rv = ra * V[p];
      S1[p] += rv;
      S2[p] = fmaf(rv, V[p], S2[p]);
    }
  }

  // ---- pair-combine ng via lane^32
#pragma unroll
  for (int p = 0; p < 16; ++p) {
    S1[p] += __shfl_xor(S1[p], 32);
    S2[p] += __shfl_xor(S2[p], 32);
  }
  rs += __shfl_xor(rs, 32);

  float* dst = cur + bid*1056;

  // ---- phase A: S1 partials -> global
  if (lane < 32) {
    float* p1 = part + wv*544 + o*17;
#pragma unroll
    for (int p = 0; p < 16; ++p) p1[p] = S1[p];
    prs[wv*32 + o] = rs;
  }
  __syncthreads();
  {
    const int pi = t >> 5, oo = t & 31;
    float s1 = 0.f;
#pragma unroll
    for (int g = 0; g < 8; ++g) s1 += part[g*544 + oo*17 + pi];
    dst[t] = s1;                            // S1 at [0..511]
    if (t < 32) {
      float r = 0.f;
#pragma unroll
      for (int g = 0; g < 8; ++g) r += prs[(g << 5) + t];
      dst[1024 + t] = r;                    // rs at [1024..1055]
    }
  }
  __syncthreads();

  // ---- phase B: S2 partials -> global
  if (lane < 32) {
    float* p2 = part + wv*544 + o*17;
#pragma unroll
    for (int p = 0; p < 16; ++p) p2[p] = S2[p];
  }
  __syncthreads();
  {
    const int pi = t >> 5, oo = t & 31;
    float s2 = 0.f;
#pragma unroll
    for (int g = 0; g < 8; ++g) s2 += part[g*544 + oo*17 + pi];
    dst[512 + t] = s2;                      // S2 at [512..1023]
  }
}

// ---- final kernel: mu/aout from last stats partials -> Out
__global__ __launch_bounds__(512, 4) void caps_final(
    const float* __restrict__ prev, const float* __restrict__ Bu,
    const float* __restrict__ Ba, float* __restrict__ Out)
{
  __shared__ float mu_t[512], lsig_t[512], rs_s[32], aout_s[32];

  const int t   = threadIdx.x;
  const int pos = blockIdx.x;
  {
    const int pi = t >> 5, oo = t & 31;
    const float* h0 = prev + (pos*2+0)*1056;
    const float* h1 = prev + (pos*2+1)*1056;
    const int idx = pi*32 + oo;
    const float s1   = h0[idx]     + h1[idx];
    const float s2   = h0[512+idx] + h1[512+idx];
    const float rsum = h0[1024+oo] + h1[1024+oo] + EPSV;
    const float mu = s1 / rsum;
    float var = s2 / rsum - mu*mu;
    var = fmaxf(var, 0.f);
    mu_t[idx]   = mu;
    lsig_t[idx] = __logf(var + EPSV);
    if (pi == 0) rs_s[oo] = rsum;
  }
  __syncthreads();
  if (t < 32) {
    float slog = 0.f;
#pragma unroll
    for (int p = 0; p < 16; ++p) slog += lsig_t[p*32 + t];
    const float cost = rs_s[t] * (16.0f*Bu[t] + 0.5f*slog);
    aout_s[t] = 1.0f / (1.0f + __expf(-(Ba[t] - cost)));
  }
  __syncthreads();
  {
    const int oo = t >> 4, pi = t & 15;
    Out[pos*512 + t] = mu_t[pi*32 + oo];
  }
  if (t < 32) Out[294912 + pos*32 + t] = aout_s[t];
}

extern "C" void kernel_launch(void* const* d_in, const int* in_sizes, int n_in,
                              void* d_out, int out_size, void* d_ws, size_t ws_size,
                              hipStream_t stream) {
  (void)in_sizes; (void)n_in; (void)ws_size; (void)out_size;
  const float* X  = (const float*)d_in[0];
  const float* A  = (const float*)d_in[1];
  const float* Wt = (const float*)d_in[2];
  const float* Bu = (const float*)d_in[3];
  const float* Ba = (const float*)d_in[4];
  float* Out = (float*)d_out;

  float* pa = (float*)d_ws;                 // parity A: 1152*1056 floats
  float* pb = pa + 1152*1056;               // parity B (total ~9.3 MB)

  hipLaunchKernelGGL(caps_stats, dim3(1152), dim3(512), 0, stream,
                     X, A, Wt, Bu, Ba, (const float*)nullptr, pa, 0);
  hipLaunchKernelGGL(caps_stats, dim3(1152), dim3(512), 0, stream,
                     X, A, Wt, Bu, Ba, pa, pb, 1);
  hipLaunchKernelGGL(caps_stats, dim3(1152), dim3(512), 0, stream,
                     X, A, Wt, Bu, Ba, pb, pa, 2);
  hipLaunchKernelGGL(caps_final, dim3(576), dim3(512), 0, stream,
                     pa, Bu, Ba, Out);
}